// Round 1
// baseline (442.607 us; speedup 1.0000x reference)
//
#include <hip/hip_runtime.h>
#include <hip/hip_bf16.h>

// Problem shapes (fixed by setup_inputs)
#define B_    1024
#define D_    768
#define POOL_ 100
#define PLEN_ 8
#define TOPK_ 3
#define EK_ELEMS (B_ * 4 * D_)           // 3,145,728
#define XB_ELEMS (B_ * 197 * D_)         // 154,976,256

// ---------------------------------------------------------------------------
// Kernel 1: per-pool-row prep: sm[k,:] = softmax(A[k,:]) (f64),
//           nK[k,:] = K[k,:] / max(||K[k,:]||, 1e-12)   (f64)
// grid = POOL_ blocks, 256 threads (4 waves)
// ---------------------------------------------------------------------------
__global__ void prep_kernel(const float* __restrict__ A, const float* __restrict__ K,
                            double* __restrict__ sm, double* __restrict__ nK) {
    const int k = blockIdx.x;
    const int t = threadIdx.x;
    const int wave = t >> 6, lane = t & 63;
    __shared__ double red[4];

    // ---- max of A row ----
    double m = -1e300;
    for (int d = t; d < D_; d += 256) m = fmax(m, (double)A[k * D_ + d]);
    #pragma unroll
    for (int off = 32; off >= 1; off >>= 1) m = fmax(m, __shfl_xor(m, off));
    if (lane == 0) red[wave] = m;
    __syncthreads();
    m = fmax(fmax(red[0], red[1]), fmax(red[2], red[3]));
    __syncthreads();

    // ---- sum of exp ----
    double s = 0.0;
    for (int d = t; d < D_; d += 256) s += exp((double)A[k * D_ + d] - m);
    #pragma unroll
    for (int off = 32; off >= 1; off >>= 1) s += __shfl_xor(s, off);
    if (lane == 0) red[wave] = s;
    __syncthreads();
    s = red[0] + red[1] + red[2] + red[3];
    __syncthreads();

    for (int d = t; d < D_; d += 256)
        sm[k * D_ + d] = exp((double)A[k * D_ + d] - m) / s;

    // ---- K row L2 norm ----
    double ss = 0.0;
    for (int d = t; d < D_; d += 256) {
        double v = (double)K[k * D_ + d];
        ss += v * v;
    }
    #pragma unroll
    for (int off = 32; off >= 1; off >>= 1) ss += __shfl_xor(ss, off);
    if (lane == 0) red[wave] = ss;
    __syncthreads();
    ss = red[0] + red[1] + red[2] + red[3];
    double n = fmax(sqrt(ss), 1e-12);

    for (int d = t; d < D_; d += 256)
        nK[k * D_ + d] = (double)K[k * D_ + d] / n;
}

// ---------------------------------------------------------------------------
// Kernel 2: per-b scoring + top-3.
// aq[b,k] = dot(xq[b]*sm[k], nK[k]) / max(||xq[b]*sm[k]||, 1e-12)
// grid = B_ blocks, 256 threads; wave w handles k = w, w+4, ...
// ---------------------------------------------------------------------------
__global__ void score_topk_kernel(const float* __restrict__ xq,
                                  const double* __restrict__ sm,
                                  const double* __restrict__ nK,
                                  int* __restrict__ idx) {
    __shared__ double s_xq[D_];
    __shared__ double s_aq[POOL_];
    const int b = blockIdx.x;
    const int t = threadIdx.x;
    const int wave = t >> 6, lane = t & 63;

    for (int d = t; d < D_; d += 256) s_xq[d] = (double)xq[b * D_ + d];
    __syncthreads();

    for (int k = wave; k < POOL_; k += 4) {
        const double* __restrict__ smk = sm + (size_t)k * D_;
        const double* __restrict__ nkk = nK + (size_t)k * D_;
        double dot = 0.0, sq = 0.0;
        for (int d = lane; d < D_; d += 64) {
            double v = s_xq[d] * smk[d];
            dot += v * nkk[d];
            sq  += v * v;
        }
        #pragma unroll
        for (int off = 32; off >= 1; off >>= 1) {
            dot += __shfl_xor(dot, off);
            sq  += __shfl_xor(sq, off);
        }
        if (lane == 0) s_aq[k] = dot / fmax(sqrt(sq), 1e-12);
    }
    __syncthreads();

    if (t == 0) {
        // top-3, ties -> lowest index (lax.top_k is stable)
        #pragma unroll
        for (int r = 0; r < TOPK_; ++r) {
            double best = -1e300; int bi = 0;
            for (int kk = 0; kk < POOL_; ++kk) {
                if (s_aq[kk] > best) { best = s_aq[kk]; bi = kk; }
            }
            idx[b * TOPK_ + r] = bi;
            s_aq[bi] = -1e300;
        }
    }
}

// ---------------------------------------------------------------------------
// Kernel 3: gather + sum over selected 3 pool rows.
// Ek[b,j,:]   (j<4)  at out + (b*4+j)*768
// Ev[b,j-4,:] (j>=4) at out + EK_ELEMS + (b*4+(j-4))*768
// grid = B_*PLEN_ blocks, 192 threads (1 float4 each: 192*4 = 768)
// ---------------------------------------------------------------------------
__global__ void gather_sum_kernel(const float* __restrict__ p,
                                  const int* __restrict__ idx,
                                  float* __restrict__ out) {
    const int bj = blockIdx.x;
    const int b = bj >> 3, j = bj & 7;
    const int i0 = idx[b * TOPK_ + 0];
    const int i1 = idx[b * TOPK_ + 1];
    const int i2 = idx[b * TOPK_ + 2];

    const float4* __restrict__ q0 = (const float4*)(p + ((size_t)(j * POOL_ + i0)) * D_);
    const float4* __restrict__ q1 = (const float4*)(p + ((size_t)(j * POOL_ + i1)) * D_);
    const float4* __restrict__ q2 = (const float4*)(p + ((size_t)(j * POOL_ + i2)) * D_);

    float* dst = (j < 4) ? out + ((size_t)b * 4 + j) * D_
                         : out + EK_ELEMS + ((size_t)b * 4 + (j - 4)) * D_;

    const int t = threadIdx.x;  // 0..191
    float4 a = q0[t], c = q1[t], e = q2[t];
    float4 r;
    r.x = a.x + c.x + e.x;
    r.y = a.y + c.y + e.y;
    r.z = a.z + c.z + e.z;
    r.w = a.w + c.w + e.w;
    ((float4*)dst)[t] = r;
}

extern "C" void kernel_launch(void* const* d_in, const int* in_sizes, int n_in,
                              void* d_out, int out_size, void* d_ws, size_t ws_size,
                              hipStream_t stream) {
    const float* x_querry = (const float*)d_in[0];   // (1024, 768)
    const float* x_block  = (const float*)d_in[1];   // (1024, 197, 768)
    const float* K        = (const float*)d_in[2];   // (100, 768)
    const float* A        = (const float*)d_in[3];   // (100, 768)
    const float* p        = (const float*)d_in[4];   // (8, 100, 768)
    // d_in[5] = l (unused)

    float* out = (float*)d_out;

    // workspace layout
    double* sm  = (double*)d_ws;                         // 100*768 f64 = 614400 B
    double* nK  = sm + (size_t)POOL_ * D_;               // 614400 B
    int*    idx = (int*)(nK + (size_t)POOL_ * D_);       // 1024*3*4 = 12288 B

    prep_kernel<<<POOL_, 256, 0, stream>>>(A, K, sm, nK);
    score_topk_kernel<<<B_, 256, 0, stream>>>(x_querry, sm, nK, idx);
    gather_sum_kernel<<<B_ * PLEN_, 192, 0, stream>>>(p, idx, out);

    // x_block passthrough (dominates runtime: ~620 MB each way)
    hipMemcpyAsync(out + 2 * (size_t)EK_ELEMS, x_block,
                   (size_t)XB_ELEMS * sizeof(float),
                   hipMemcpyDeviceToDevice, stream);
}

// Round 2
// 365.107 us; speedup vs baseline: 1.2123x; 1.2123x over previous
//
#include <hip/hip_runtime.h>
#include <hip/hip_bf16.h>

// Problem shapes (fixed by setup_inputs)
#define B_    1024
#define D_    768
#define POOL_ 100
#define PLEN_ 8
#define TOPK_ 3
#define EK_ELEMS (B_ * 4 * D_)           // 3,145,728
#define XB_ELEMS (B_ * 197 * D_)         // 154,976,256
#define XB_F4   (XB_ELEMS / 4)           // 38,744,064 float4s
#define NGATHER (B_ * PLEN_)             // 8192 gather blocks
#define NCOPY   8192                     // copy blocks

typedef float f4_t __attribute__((ext_vector_type(4)));

// ---------------------------------------------------------------------------
// Kernel 1: per-pool-row prep: sm[k,:] = softmax(A[k,:]) (f64),
//           nK[k,:] = K[k,:] / max(||K[k,:]||, 1e-12)   (f64)
// grid = POOL_ blocks, 256 threads (4 waves)
// ---------------------------------------------------------------------------
__global__ void prep_kernel(const float* __restrict__ A, const float* __restrict__ K,
                            double* __restrict__ sm, double* __restrict__ nK) {
    const int k = blockIdx.x;
    const int t = threadIdx.x;
    const int wave = t >> 6, lane = t & 63;
    __shared__ double red[4];

    // ---- max of A row ----
    double m = -1e300;
    for (int d = t; d < D_; d += 256) m = fmax(m, (double)A[k * D_ + d]);
    #pragma unroll
    for (int off = 32; off >= 1; off >>= 1) m = fmax(m, __shfl_xor(m, off));
    if (lane == 0) red[wave] = m;
    __syncthreads();
    m = fmax(fmax(red[0], red[1]), fmax(red[2], red[3]));
    __syncthreads();

    // ---- sum of exp ----
    double s = 0.0;
    for (int d = t; d < D_; d += 256) s += exp((double)A[k * D_ + d] - m);
    #pragma unroll
    for (int off = 32; off >= 1; off >>= 1) s += __shfl_xor(s, off);
    if (lane == 0) red[wave] = s;
    __syncthreads();
    s = red[0] + red[1] + red[2] + red[3];
    __syncthreads();

    for (int d = t; d < D_; d += 256)
        sm[k * D_ + d] = exp((double)A[k * D_ + d] - m) / s;

    // ---- K row L2 norm ----
    double ss = 0.0;
    for (int d = t; d < D_; d += 256) {
        double v = (double)K[k * D_ + d];
        ss += v * v;
    }
    #pragma unroll
    for (int off = 32; off >= 1; off >>= 1) ss += __shfl_xor(ss, off);
    if (lane == 0) red[wave] = ss;
    __syncthreads();
    ss = red[0] + red[1] + red[2] + red[3];
    double n = fmax(sqrt(ss), 1e-12);

    for (int d = t; d < D_; d += 256)
        nK[k * D_ + d] = (double)K[k * D_ + d] / n;
}

// ---------------------------------------------------------------------------
// Kernel 2: per-b scoring + top-3 (f64 to track the numpy f64 reference).
// grid = B_ blocks, 256 threads; wave w handles k = w, w+4, ...
// ---------------------------------------------------------------------------
__global__ void score_topk_kernel(const float* __restrict__ xq,
                                  const double* __restrict__ sm,
                                  const double* __restrict__ nK,
                                  int* __restrict__ idx) {
    __shared__ double s_xq[D_];
    __shared__ double s_aq[POOL_];
    const int b = blockIdx.x;
    const int t = threadIdx.x;
    const int wave = t >> 6, lane = t & 63;

    for (int d = t; d < D_; d += 256) s_xq[d] = (double)xq[b * D_ + d];
    __syncthreads();

    for (int k = wave; k < POOL_; k += 4) {
        const double* __restrict__ smk = sm + (size_t)k * D_;
        const double* __restrict__ nkk = nK + (size_t)k * D_;
        double dot = 0.0, sq = 0.0;
        for (int d = lane; d < D_; d += 64) {
            double v = s_xq[d] * smk[d];
            dot += v * nkk[d];
            sq  += v * v;
        }
        #pragma unroll
        for (int off = 32; off >= 1; off >>= 1) {
            dot += __shfl_xor(dot, off);
            sq  += __shfl_xor(sq, off);
        }
        if (lane == 0) s_aq[k] = dot / fmax(sqrt(sq), 1e-12);
    }
    __syncthreads();

    if (t == 0) {
        // top-3, ties -> lowest index (lax.top_k is stable)
        #pragma unroll
        for (int r = 0; r < TOPK_; ++r) {
            double best = -1e300; int bi = 0;
            for (int kk = 0; kk < POOL_; ++kk) {
                if (s_aq[kk] > best) { best = s_aq[kk]; bi = kk; }
            }
            idx[b * TOPK_ + r] = bi;
            s_aq[bi] = -1e300;
        }
    }
}

// ---------------------------------------------------------------------------
// Kernel 3 (fused): gather+sum of selected pool rows, then x_block passthrough.
// Blocks [0, NGATHER): gather for (b = blk>>3, j = blk&7); threads 0..191 each
//   handle one float4 of the 768-wide row.
// Blocks [NGATHER, NGATHER+NCOPY): grid-stride nontemporal float4 copy of
//   x_block (620 MB) into the tail of out.
// ---------------------------------------------------------------------------
__global__ void __launch_bounds__(256)
gather_copy_kernel(const float* __restrict__ p,
                   const int* __restrict__ idx,
                   const float* __restrict__ xb,
                   float* __restrict__ out) {
    if (blockIdx.x < NGATHER) {
        const int t = threadIdx.x;
        if (t >= 192) return;
        const int b = blockIdx.x >> 3, j = blockIdx.x & 7;
        const int i0 = idx[b * TOPK_ + 0];
        const int i1 = idx[b * TOPK_ + 1];
        const int i2 = idx[b * TOPK_ + 2];

        const f4_t* __restrict__ q0 = (const f4_t*)(p + ((size_t)(j * POOL_ + i0)) * D_);
        const f4_t* __restrict__ q1 = (const f4_t*)(p + ((size_t)(j * POOL_ + i1)) * D_);
        const f4_t* __restrict__ q2 = (const f4_t*)(p + ((size_t)(j * POOL_ + i2)) * D_);

        float* dst = (j < 4) ? out + ((size_t)b * 4 + j) * D_
                             : out + EK_ELEMS + ((size_t)b * 4 + (j - 4)) * D_;

        f4_t r = q0[t] + q1[t] + q2[t];
        ((f4_t*)dst)[t] = r;
    } else {
        const f4_t* __restrict__ src = (const f4_t*)xb;
        f4_t* __restrict__ dst = (f4_t*)(out + 2 * (size_t)EK_ELEMS);
        size_t tid = (size_t)(blockIdx.x - NGATHER) * 256 + threadIdx.x;
        const size_t stride = (size_t)NCOPY * 256;
        for (size_t i = tid; i < (size_t)XB_F4; i += stride) {
            f4_t v = __builtin_nontemporal_load(&src[i]);
            __builtin_nontemporal_store(v, &dst[i]);
        }
    }
}

extern "C" void kernel_launch(void* const* d_in, const int* in_sizes, int n_in,
                              void* d_out, int out_size, void* d_ws, size_t ws_size,
                              hipStream_t stream) {
    const float* x_querry = (const float*)d_in[0];   // (1024, 768)
    const float* x_block  = (const float*)d_in[1];   // (1024, 197, 768)
    const float* K        = (const float*)d_in[2];   // (100, 768)
    const float* A        = (const float*)d_in[3];   // (100, 768)
    const float* p        = (const float*)d_in[4];   // (8, 100, 768)
    // d_in[5] = l (unused)

    float* out = (float*)d_out;

    // workspace layout
    double* sm  = (double*)d_ws;                         // 100*768 f64 = 614400 B
    double* nK  = sm + (size_t)POOL_ * D_;               // 614400 B
    int*    idx = (int*)(nK + (size_t)POOL_ * D_);       // 1024*3*4 = 12288 B

    prep_kernel<<<POOL_, 256, 0, stream>>>(A, K, sm, nK);
    score_topk_kernel<<<B_, 256, 0, stream>>>(x_querry, sm, nK, idx);
    gather_copy_kernel<<<NGATHER + NCOPY, 256, 0, stream>>>(p, idx, x_block, out);
}